// Round 1
// baseline (1865.859 us; speedup 1.0000x reference)
//
#include <hip/hip_runtime.h>
#include <hip/hip_bf16.h>

// Problem constants
#define M_TOK 16384
#define N_OUT 6144
#define K_IN  4096
#define SBLK  128   // scale block

typedef __bf16 bf16x8 __attribute__((ext_vector_type(8)));
typedef float  f32x4  __attribute__((ext_vector_type(4)));

// fp32 -> bf16 round-to-nearest-even (bit trick; inputs are normal floats)
__device__ __forceinline__ unsigned short f2bf(float f) {
    unsigned int u = __builtin_bit_cast(unsigned int, f);
    u += 0x7fffu + ((u >> 16) & 1u);
    return (unsigned short)(u >> 16);
}

// async global->LDS, 16 B per lane, LDS dest = wave-uniform base + lane*16
__device__ __forceinline__ void async16(const void* g, void* l) {
    __builtin_amdgcn_global_load_lds(
        (const __attribute__((address_space(1))) unsigned int*)g,
        (__attribute__((address_space(3))) unsigned int*)l,
        16, 0, 0);
}

// ---- prep kernel 1: x fp32 -> bf16 (row-major [M, K], K-contiguous) ----
__global__ __launch_bounds__(256) void cvt_x_kernel(
        const float* __restrict__ x, unsigned short* __restrict__ out) {
    int i = blockIdx.x * 256 + threadIdx.x;          // float4 index
    float4 v = ((const float4*)x)[i];
    ushort4 o;
    o.x = f2bf(v.x); o.y = f2bf(v.y); o.z = f2bf(v.z); o.w = f2bf(v.w);
    ((ushort4*)out)[i] = o;
}

// ---- prep kernel 2: w fp32 * blockscale -> bf16 ([N, K], K-contiguous) ----
__global__ __launch_bounds__(256) void cvt_w_kernel(
        const float* __restrict__ w, const float* __restrict__ s,
        unsigned short* __restrict__ out) {
    int i = blockIdx.x * 256 + threadIdx.x;          // float4 index
    int e = i << 2;                                  // element index
    int o = e >> 12;                                 // / K_IN
    int k = e & (K_IN - 1);
    // 4 consecutive k share one 128-block (128 % 4 == 0)
    float scale = s[(o >> 7) * (K_IN / SBLK) + (k >> 7)];
    float4 v = ((const float4*)w)[i];
    ushort4 r;
    r.x = f2bf(v.x * scale); r.y = f2bf(v.y * scale);
    r.z = f2bf(v.z * scale); r.w = f2bf(v.w * scale);
    ((ushort4*)out)[i] = r;
}

// ---- GEMM: C[M,N] = A[M,K] * B[N,K]^T, bf16 in, fp32 out ----
// 128x128 tile, BK=32, 256 threads = 4 waves (2x2), each wave 4x4 MFMA 16x16x32
__global__ __launch_bounds__(256) void gemm_bt_kernel(
        const unsigned short* __restrict__ A,
        const unsigned short* __restrict__ B,
        float* __restrict__ C) {
    // Unpadded: global_load_lds dest is wave-uniform base + lane*16 (m104/m108)
    __shared__ __attribute__((aligned(16))) unsigned short ldsA[128 * 32];
    __shared__ __attribute__((aligned(16))) unsigned short ldsB[128 * 32];

    const int tid  = threadIdx.x;
    const int wave = tid >> 6;
    const int lane = tid & 63;
    const int bn = blockIdx.x;   // N/128 = 48
    const int bm = blockIdx.y;   // M/128 = 128
    const int wm = wave >> 1;    // 0..1
    const int wn = wave & 1;     // 0..1
    const int lr = lane & 15;    // row within 16-tile
    const int lk = lane >> 4;    // k-group 0..3 (8 bf16 each)

    f32x4 acc[4][4];
#pragma unroll
    for (int mi = 0; mi < 4; ++mi)
#pragma unroll
        for (int ni = 0; ni < 4; ++ni)
            acc[mi][ni] = {0.f, 0.f, 0.f, 0.f};

    const unsigned short* Abase = A + (size_t)(bm * 128) * K_IN;
    const unsigned short* Bbase = B + (size_t)(bn * 128) * K_IN;

    for (int k0 = 0; k0 < K_IN; k0 += 32) {
        // stage 128x32 A-tile and B-tile: 512 x 16B each, 2 rounds of 256 lanes
#pragma unroll
        for (int j = 0; j < 2; ++j) {
            int e = j * 256 + wave * 64 + lane;          // 0..511
            // row = e>>2 (64 B = 4 lanes per 32-elem row), k-off = (e&3)*8 elems
            const unsigned short* ga = Abase + (size_t)(e >> 2) * K_IN + k0 + (e & 3) * 8;
            const unsigned short* gb = Bbase + (size_t)(e >> 2) * K_IN + k0 + (e & 3) * 8;
            // wave-uniform LDS base; lanes land at +lane*16 automatically
            unsigned short* la = ldsA + (size_t)(j * 256 + wave * 64) * 8;
            unsigned short* lb = ldsB + (size_t)(j * 256 + wave * 64) * 8;
            async16(ga, la);
            async16(gb, lb);
        }
        __syncthreads();   // drains vmcnt for global_load_lds

        bf16x8 af[4], bf[4];
#pragma unroll
        for (int mi = 0; mi < 4; ++mi)
            af[mi] = *(const bf16x8*)(ldsA + (wm * 64 + mi * 16 + lr) * 32 + lk * 8);
#pragma unroll
        for (int ni = 0; ni < 4; ++ni)
            bf[ni] = *(const bf16x8*)(ldsB + (wn * 64 + ni * 16 + lr) * 32 + lk * 8);

#pragma unroll
        for (int mi = 0; mi < 4; ++mi)
#pragma unroll
            for (int ni = 0; ni < 4; ++ni)
                acc[mi][ni] = __builtin_amdgcn_mfma_f32_16x16x32_bf16(
                    af[mi], bf[ni], acc[mi][ni], 0, 0, 0);

        __syncthreads();   // protect LDS before next stage
    }

    // epilogue: C/D layout col = lane&15, row = (lane>>4)*4 + reg  (m89/m91)
    const int r0 = bm * 128 + wm * 64;
    const int c0 = bn * 128 + wn * 64;
#pragma unroll
    for (int mi = 0; mi < 4; ++mi) {
#pragma unroll
        for (int ni = 0; ni < 4; ++ni) {
            int col  = c0 + ni * 16 + lr;
            int rowb = r0 + mi * 16 + lk * 4;
#pragma unroll
            for (int r = 0; r < 4; ++r)
                C[(size_t)(rowb + r) * N_OUT + col] = acc[mi][ni][r];
        }
    }
}

extern "C" void kernel_launch(void* const* d_in, const int* in_sizes, int n_in,
                              void* d_out, int out_size, void* d_ws, size_t ws_size,
                              hipStream_t stream) {
    const float* x = (const float*)d_in[0];                 // [16384, 4096]
    const float* w = (const float*)d_in[1];                 // [6144, 4096]
    const float* s = (const float*)d_in[2];                 // [48, 32]
    float* out = (float*)d_out;                             // [16384, 6144]

    unsigned short* xb = (unsigned short*)d_ws;             // 134 MB
    unsigned short* wb = xb + (size_t)M_TOK * K_IN;         // +50 MB

    // x: 67108864 elems / 4 = 16777216 float4s / 256 = 65536 blocks
    cvt_x_kernel<<<65536, 256, 0, stream>>>(x, xb);
    // w: 25165824 elems / 4 = 6291456 float4s / 256 = 24576 blocks
    cvt_w_kernel<<<24576, 256, 0, stream>>>(w, s, wb);

    dim3 grid(N_OUT / 128, M_TOK / 128);                    // 48 x 128
    gemm_bt_kernel<<<grid, 256, 0, stream>>>(xb, wb, out);
}